// Round 9
// baseline (430.544 us; speedup 1.0000x reference)
//
#include <hip/hip_runtime.h>
#include <hip/hip_fp16.h>
#include <math.h>

#define IN0    128
#define HEADS  4
#define CDIM   64
#define HC     256
#define SLOPE  0.2f
#define NPAD   50176   // 392*128, row padding
#define BK     32      // k-chunk (halves) = 64 B

typedef __attribute__((ext_vector_type(8))) _Float16 f16x8;
typedef __attribute__((ext_vector_type(4))) float f32x4;

__device__ __forceinline__ float h2f(ushort u) {
    __half h = *(const __half*)&u;
    return __half2float(h);
}
__device__ __forceinline__ ushort f2h(float f) {
    __half h = __float2half_rn(f);
    return *(ushort*)&h;
}

// ---------------- fused prep: degree + xconv(fp16,chunked) + wconv(fp16,chunked) x3 ----------------

__device__ __forceinline__ void wconv_body(const float* __restrict__ W,
                                           ushort* __restrict__ Wc, int K, int b) {
    int tid = b * 256 + threadIdx.x;     // K*256 threads
    int n = tid & 255;                   // output col (coalesced read)
    int k = tid >> 8;
    if (k >= K) return;
    Wc[(size_t)(k >> 5) * (HC * BK) + n * BK + (k & 31)] = f2h(W[(size_t)k * HC + n]);
}

__global__ __launch_bounds__(256) void k_prep(
        const int* __restrict__ dst_rand, int E_rand, int* __restrict__ deg,
        const float* __restrict__ x0, ushort* __restrict__ Xc, int totalx,
        const float* __restrict__ W0, ushort* __restrict__ Wc0,
        const float* __restrict__ W1, ushort* __restrict__ Wc1,
        const float* __restrict__ W2, ushort* __restrict__ Wc2,
        int B0, int B1) {
    int b = blockIdx.x;
    if (b < B0) {
        int i = b * 256 + threadIdx.x;
        if (i < E_rand) atomicAdd(&deg[dst_rand[i]], 1);
        return;
    }
    b -= B0;
    if (b < B1) {                        // xconv: x0 [N][128] -> Xc [4][NPAD][32]
        int i = b * 256 + threadIdx.x;
        if (i < totalx) {
            int n = i >> 7, k = i & 127;
            Xc[(size_t)(k >> 5) * (NPAD * BK) + n * BK + (k & 31)] = f2h(x0[i]);
        }
        return;
    }
    b -= B1;
    if (b < 128) { wconv_body(W0, Wc0, 128, b); return; }
    b -= 128;
    if (b < 256) { wconv_body(W1, Wc1, 256, b); return; }
    b -= 256;
    wconv_body(W2, Wc2, 256, b);
}

// ---------------- single-kernel scan (prefix-of-prefixes brute force) ----------------

__global__ __launch_bounds__(1024) void k_scan(const int* __restrict__ deg, int Nn,
                                               int* __restrict__ rowptr,
                                               int* __restrict__ cur) {
    __shared__ int smem[1024];
    int tid = threadIdx.x;
    int pre = 0;
    int limit = blockIdx.x * 1024;
    for (int i = tid; i < limit; i += 1024) pre += deg[i];
    smem[tid] = pre;
    __syncthreads();
    #pragma unroll
    for (int d = 512; d >= 1; d >>= 1) {
        if (tid < d) smem[tid] += smem[tid + d];
        __syncthreads();
    }
    int s_off = smem[0];
    __syncthreads();
    int i = blockIdx.x * 1024 + tid;
    int v = (i < Nn) ? deg[i] : 0;
    smem[tid] = v;
    __syncthreads();
    #pragma unroll
    for (int d = 1; d < 1024; d <<= 1) {
        int t = 0;
        if (tid >= d) t = smem[tid - d];
        __syncthreads();
        smem[tid] += t;
        __syncthreads();
    }
    if (i < Nn) {
        int e = s_off + smem[tid] - v;
        rowptr[i] = e;
        cur[i] = e;
    }
    if (blockIdx.x == gridDim.x - 1 && tid == 1023) rowptr[Nn] = s_off + smem[1023];
}

__global__ void k_scatter(const int* __restrict__ src, const int* __restrict__ dst, int E_rand,
                          int* __restrict__ cur, int* __restrict__ csr_src,
                          int* __restrict__ csr_dst) {
    int i = blockIdx.x * blockDim.x + threadIdx.x;
    if (i < E_rand) {
        int d = dst[i];
        int p = atomicAdd(&cur[d], 1);
        csr_src[p] = src[i];
        csr_dst[p] = d;
    }
}

// ---------------- fused GEMM + attention scores (fp16 MFMA, no LDS, chunked operands) ----------------
// H row-major [NPAD][HC]; a-tables interleaved [n][4] (one line per endpoint in k_edgew).

template<int K>
__global__ __launch_bounds__(256) void k_gemm_att(const ushort* __restrict__ Xc,
                                                  const ushort* __restrict__ Wc,
                                                  const float* __restrict__ attS,
                                                  const float* __restrict__ attD,
                                                  ushort* __restrict__ H16out,
                                                  float* __restrict__ a_src_v,
                                                  float* __restrict__ a_dst_v,
                                                  int M) {
    int id    = blockIdx.x;
    int group = id >> 4;
    int sub   = id & 15;
    int row0  = (group * 8 + (sub & 7)) * 128;
    int colb  = sub >> 3;
    int col0  = colb * 128;

    int t    = threadIdx.x;
    int wave = t >> 6, lane = t & 63;
    int wm = wave & 1, wn = wave >> 1;
    int quad = lane >> 4, l16 = lane & 15;

    f32x4 acc[4][4];
    #pragma unroll
    for (int i = 0; i < 4; i++)
        #pragma unroll
        for (int j = 0; j < 4; j++) acc[i][j] = (f32x4){0.f, 0.f, 0.f, 0.f};

    constexpr int NK = K / BK;
    #pragma unroll
    for (int kc = 0; kc < NK; kc++) {
        f16x8 a[4], b[4];
        #pragma unroll
        for (int mt = 0; mt < 4; mt++) {
            size_t ga = (size_t)kc * (NPAD * BK)
                      + (size_t)(row0 + wm * 64 + mt * 16 + l16) * BK + quad * 8;
            a[mt] = *(const f16x8*)&Xc[ga];
        }
        #pragma unroll
        for (int nt = 0; nt < 4; nt++) {
            size_t gb = (size_t)kc * (HC * BK)
                      + (size_t)(col0 + wn * 64 + nt * 16 + l16) * BK + quad * 8;
            b[nt] = *(const f16x8*)&Wc[gb];
        }
        #pragma unroll
        for (int mt = 0; mt < 4; mt++)
            #pragma unroll
            for (int nt = 0; nt < 4; nt++)
                acc[mt][nt] = __builtin_amdgcn_mfma_f32_16x16x32_f16(a[mt], b[nt], acc[mt][nt], 0, 0, 0);
    }

    // epilogue 1: store H as fp16 row-major (C/D layout col=lane&15, row=quad*4+reg)
    #pragma unroll
    for (int mt = 0; mt < 4; mt++) {
        #pragma unroll
        for (int r = 0; r < 4; r++) {
            int row = row0 + wm*64 + mt*16 + quad*4 + r;
            if (row >= M) continue;
            #pragma unroll
            for (int nt = 0; nt < 4; nt++) {
                size_t idx = (size_t)row * HC + col0 + wn*64 + nt*16 + l16;
                H16out[idx] = f2h(acc[mt][nt][r]);
            }
        }
    }

    // epilogue 2: att score dots; this wave's cols = head (2*colb + wn).
    int headw = colb * 2 + wn;
    float sS[4], sD[4];
    #pragma unroll
    for (int nt = 0; nt < 4; nt++) {
        sS[nt] = attS[headw * CDIM + nt*16 + l16];
        sD[nt] = attD[headw * CDIM + nt*16 + l16];
    }
    #pragma unroll
    for (int mt = 0; mt < 4; mt++) {
        #pragma unroll
        for (int r = 0; r < 4; r++) {
            float ps = 0.f, pd = 0.f;
            #pragma unroll
            for (int nt = 0; nt < 4; nt++) {
                float av = acc[mt][nt][r];
                ps += av * sS[nt];
                pd += av * sD[nt];
            }
            #pragma unroll
            for (int d = 1; d <= 8; d <<= 1) {
                ps += __shfl_xor(ps, d);
                pd += __shfl_xor(pd, d);
            }
            int row = row0 + wm*64 + mt*16 + quad*4 + r;
            if (l16 == 0 && row < M) {
                a_src_v[(size_t)row * 4 + headw] = ps;   // interleaved [n][4]
                a_dst_v[(size_t)row * 4 + headw] = pd;
            }
        }
    }
}

// ---------------- edge weights: w[h][p] = exp(leaky(a_src[src]+a_dst[dst])) ----------------
// Edge-parallel, coalesced; hoists the ex-phase (a-gather + exp) out of the aggregate,
// where it was duplicated across both half-waves (r8: 54% VALUBusy).

__global__ __launch_bounds__(256) void k_edgew(
        const int* __restrict__ csr_src, const int* __restrict__ csr_dst, int E_rand,
        const float* __restrict__ aI_src, const float* __restrict__ aI_dst,
        float* __restrict__ wpl, int EPAD) {
    int p = blockIdx.x * 256 + threadIdx.x;
    if (p >= E_rand) return;
    int s = csr_src[p], d = csr_dst[p];
    float4 as = *(const float4*)&aI_src[(size_t)s * 4];
    float4 ad = *(const float4*)&aI_dst[(size_t)d * 4];
    float e0 = as.x + ad.x, e1 = as.y + ad.y, e2 = as.z + ad.z, e3 = as.w + ad.w;
    e0 = fmaxf(e0, SLOPE * e0); e1 = fmaxf(e1, SLOPE * e1);
    e2 = fmaxf(e2, SLOPE * e2); e3 = fmaxf(e3, SLOPE * e3);
    wpl[0 * (size_t)EPAD + p] = __expf(e0);
    wpl[1 * (size_t)EPAD + p] = __expf(e1);
    wpl[2 * (size_t)EPAD + p] = __expf(e2);
    wpl[3 * (size_t)EPAD + p] = __expf(e3);
}

// ---------------- aggregation: r8 2-half XCD structure, zero-shfl loop via w-stream ----------------
// Wave = (node, half); slice = blockIdx&1 -> even XCDs ch 0-127, odd 128-255 (proven r8:
// FETCH 210->189 MB). r8's loss was duplicated ex-phase + shfl broadcasts (VALU 38 us).
// Now: NO ex phase, NO shfls in the loop. Lane (e2,ha2,c4) loads its edges' s and w
// DIRECTLY (16 lanes share each address -> HW broadcast, L1-hot sequential lines) and
// gathers 2 edges x 128 B contiguous. Denominator = sum of w (xor-32 reduce only).
// OOB slots masked via cndmask on (w, s); slack reads land in mapped workspace.

__global__ __launch_bounds__(256) void k_aggregate(
        const ushort* __restrict__ H16,     // [NPAD][HC] fp16 row-major
        const float* __restrict__ aI_src,   // [Nn][4] (self-loop only)
        const float* __restrict__ aI_dst,   // [Nn][4]
        const int* __restrict__ rowptr, const int* __restrict__ csr_src,  // +slack
        const float* __restrict__ wpl, int EPAD,
        const float* __restrict__ bias,
        float* __restrict__ out_f32,        // nullable
        ushort* __restrict__ out_h16c,      // nullable (fp16, CHUNKED for next GEMM)
        int Nn) {
    int wave  = threadIdx.x >> 6;
    int lane  = threadIdx.x & 63;
    int slice = blockIdx.x & 1;             // channel half == XCD parity
    int n = (blockIdx.x >> 1) * 4 + wave;
    if (n >= Nn) return;

    int e2  = lane >> 5;                    // edge sub-slot 0/1
    int ha2 = (lane >> 4) & 1;              // head within half
    int c4  = (lane & 15) * 4;              // channel base within head
    int chS = ha2 * CDIM + c4;              // channel within half (0..124)
    int hgl = slice * 2 + ha2;              // global head for this lane

    int beg = rowptr[n], end = rowptr[n + 1];
    int deg = end - beg;
    const float* wh = wpl + (size_t)hgl * EPAD;
    const char* Hb = (const char*)H16 + (size_t)(slice * 128 + chS) * 2;

    float wsum = 0.f;
    float4 acc = make_float4(0.f, 0.f, 0.f, 0.f);

    for (int j = 0; j < deg; j += 4) {
        int p0 = beg + j + e2;
        int p1 = p0 + 2;
        bool m0 = (j + e2)     < deg;
        bool m1 = (j + e2 + 2) < deg;
        int s0 = csr_src[p0];               // slack-padded; 16 lanes broadcast
        int s1 = csr_src[p1];
        float w0 = wh[p0];
        float w1 = wh[p1];
        s0 = m0 ? s0 : 0;  w0 = m0 ? w0 : 0.f;
        s1 = m1 ? s1 : 0;  w1 = m1 ? w1 : 0.f;
        ushort4 u0 = *(const ushort4*)(Hb + (size_t)s0 * (HC * 2));
        ushort4 u1 = *(const ushort4*)(Hb + (size_t)s1 * (HC * 2));
        wsum += w0 + w1;
        acc.x += w0 * h2f(u0.x); acc.y += w0 * h2f(u0.y);
        acc.z += w0 * h2f(u0.z); acc.w += w0 * h2f(u0.w);
        acc.x += w1 * h2f(u1.x); acc.y += w1 * h2f(u1.y);
        acc.z += w1 * h2f(u1.z); acc.w += w1 * h2f(u1.w);
    }

    // reduce over the e2 split (bit 5); every lane then holds full sums for its head
    wsum  += __shfl_xor(wsum, 32);
    acc.x += __shfl_xor(acc.x, 32);
    acc.y += __shfl_xor(acc.y, 32);
    acc.z += __shfl_xor(acc.z, 32);
    acc.w += __shfl_xor(acc.w, 32);

    // self-loop (lane-local; no broadcast needed)
    float es = aI_src[(size_t)n * 4 + hgl] + aI_dst[(size_t)n * 4 + hgl];
    es = fmaxf(es, SLOPE * es);
    float exs = __expf(es);

    ushort4 us = *(const ushort4*)(Hb + (size_t)n * (HC * 2));
    float rden = 1.f / (wsum + exs + 1e-16f);
    int ch = slice * 128 + chS;
    float4 b = *(const float4*)&bias[ch];
    float4 o;
    o.x = fmaxf((acc.x + exs * h2f(us.x)) * rden + b.x, 0.f);
    o.y = fmaxf((acc.y + exs * h2f(us.y)) * rden + b.y, 0.f);
    o.z = fmaxf((acc.z + exs * h2f(us.z)) * rden + b.z, 0.f);
    o.w = fmaxf((acc.w + exs * h2f(us.w)) * rden + b.w, 0.f);

    if (e2 == 0) {                          // lanes 0..31: 128 ch = 512B f32 contiguous
        if (out_f32) {
            *(float4*)&out_f32[(size_t)n * HC + ch] = o;
        }
        if (out_h16c) {
            size_t idx = (size_t)(ch >> 5) * (NPAD * BK) + (size_t)n * BK + (ch & 31);
            *(ushort4*)&out_h16c[idx] = make_ushort4(f2h(o.x), f2h(o.y), f2h(o.z), f2h(o.w));
        }
    }
}

// ---------------- launch ----------------

extern "C" void kernel_launch(void* const* d_in, const int* in_sizes, int n_in,
                              void* d_out, int out_size, void* d_ws, size_t ws_size,
                              hipStream_t stream) {
    const float* x0   = (const float*)d_in[0];
    const int*   eidx = (const int*)d_in[1];
    int Nn = in_sizes[0] / IN0;     // 50000
    int E  = in_sizes[1] / 2;       // 850000
    int E_rand = E - Nn;            // 800000 random edges; self-loops inline
    const int* srcp = eidx;
    const int* dstp = eidx + E;

    const float* Wl[3]    = {(const float*)d_in[2],  (const float*)d_in[6],  (const float*)d_in[10]};
    const float* attS[3]  = {(const float*)d_in[3],  (const float*)d_in[7],  (const float*)d_in[11]};
    const float* attD[3]  = {(const float*)d_in[4],  (const float*)d_in[8],  (const float*)d_in[12]};
    const float* biasl[3] = {(const float*)d_in[5],  (const float*)d_in[9],  (const float*)d_in[13]};
    int Kdims[3] = {IN0, HC, HC};

    int EPAD = E_rand + 8;          // slack for unconditional 4-wide loop reads

    // workspace carve
    char* p = (char*)d_ws;
    ushort* h16    = (ushort*)p; p += (size_t)NPAD * HC * sizeof(ushort);
    ushort* Xc     = (ushort*)p; p += (size_t)NPAD * HC * sizeof(ushort);   // chunked
    float*  a_src_v= (float*)p;  p += (size_t)Nn * HEADS * sizeof(float);   // [Nn][4]
    float*  a_dst_v= (float*)p;  p += (size_t)Nn * HEADS * sizeof(float);   // [Nn][4]
    int*    rowptr = (int*)p;    p += (size_t)(Nn + 1) * sizeof(int);
    int*    deg    = (int*)p;    p += (size_t)Nn * sizeof(int);
    int*    cur    = (int*)p;    p += (size_t)Nn * sizeof(int);
    int*    csr_src= (int*)p;    p += (size_t)EPAD * sizeof(int);
    int*    csr_dst= (int*)p;    p += (size_t)E_rand * sizeof(int);
    float*  wpl    = (float*)p;  p += (size_t)HEADS * EPAD * sizeof(float); // [4][EPAD]
    ushort* Wc[3];
    for (int l = 0; l < 3; l++) {
        Wc[l] = (ushort*)p; p += (size_t)HC * Kdims[l] * sizeof(ushort);
    }

    int NB = (Nn + 1023) / 1024;
    int B0 = (E_rand + 255) / 256;
    int B1 = (Nn * IN0 + 255) / 256;
    int Bprep = B0 + B1 + 128 + 256 + 256;

    hipMemsetAsync(deg, 0, (size_t)Nn * sizeof(int), stream);
    k_prep<<<Bprep, 256, 0, stream>>>(dstp, E_rand, deg,
                                      x0, Xc, Nn * IN0,
                                      Wl[0], Wc[0], Wl[1], Wc[1], Wl[2], Wc[2],
                                      B0, B1);
    k_scan<<<NB, 1024, 0, stream>>>(deg, Nn, rowptr, cur);
    k_scatter<<<(E_rand + 255) / 256, 256, 0, stream>>>(srcp, dstp, E_rand, cur,
                                                        csr_src, csr_dst);

    dim3 g(784);                   // 49 groups x (8 row-blocks x 2 col-blocks), XCD-swizzled
    dim3 ge((E_rand + 255) / 256);
    dim3 ga(2 * ((Nn + 3) / 4));   // (node-group x half); half = bid&1 -> XCD parity
    for (int l = 0; l < 3; l++) {
        if (l == 0)
            k_gemm_att<128><<<g, 256, 0, stream>>>(Xc, Wc[l], attS[l], attD[l],
                                                   h16, a_src_v, a_dst_v, Nn);
        else
            k_gemm_att<256><<<g, 256, 0, stream>>>(Xc, Wc[l], attS[l], attD[l],
                                                   h16, a_src_v, a_dst_v, Nn);
        k_edgew<<<ge, 256, 0, stream>>>(csr_src, csr_dst, E_rand,
                                        a_src_v, a_dst_v, wpl, EPAD);
        if (l < 2) {
            k_aggregate<<<ga, 256, 0, stream>>>(h16, a_src_v, a_dst_v, rowptr, csr_src,
                                                wpl, EPAD, biasl[l], nullptr, Xc, Nn);
        } else {
            k_aggregate<<<ga, 256, 0, stream>>>(h16, a_src_v, a_dst_v, rowptr, csr_src,
                                                wpl, EPAD, biasl[l], (float*)d_out, nullptr, Nn);
        }
    }
}